// Round 4
// baseline (1194.730 us; speedup 1.0000x reference)
//
#include <hip/hip_runtime.h>
#include <hip/hip_bf16.h>

// ---------------------------------------------------------------------------
// LlamaAttentionWeight: fused QKV projection (fp32 via bf16 split-GEMM) + RoPE
//   x:(2,8192,2048) wq:(2048,2048) wk:(512,2048) wv:(512,2048) pos_offset:int
//   out: qh(2,16,8192,128) | kh(2,4,8192,128) | vh(2,4,8192,128)  (fp32, concat)
//
// C = xhi.whi + xhi.wlo + xlo.whi  (bf16 split products, error ~2^-17)
// One logical GEMM M=16384 N=3072 K'=96x64, segment kt selects base pointers:
//   kt in [0,32): (Ahi,Bhi)  [32,64): (Ahi,Blo)  [64,96): (Alo,Bhi)
// GEMM: m97 structure, 128x128 tile, BK=64, 4 waves, global_load_lds(16B),
//       mfma_f32_16x16x32_bf16 (short8 operands per guide §3). Wave owns cols
//       {wc*32..+32} U {wc*32+64..+96} so the RoPE pair (d, d+64) sits in the
//       same lane -> in-register RoPE epilogue, no scratch round-trip.
// Fallback path (ws_size too small): naive LDS-staged fp32 kernel, no ws use.
// ---------------------------------------------------------------------------

typedef __attribute__((ext_vector_type(8))) short short8;   // 8 bf16 (4 VGPR)
typedef __attribute__((ext_vector_type(4))) float f32x4;

#define Q_BLOCK  33554432u   // 2*16*8192*128
#define V_BASE   41943040u   // Q_BLOCK + 2*4*8192*128

__device__ __forceinline__ unsigned short f2bf(float f) {
  unsigned u = __float_as_uint(f);
  u += 0x7FFFu + ((u >> 16) & 1u);       // RNE
  return (unsigned short)(u >> 16);
}
__device__ __forceinline__ float bf2f(unsigned short h) {
  return __uint_as_float(((unsigned)h) << 16);
}

// ---------------- prep: split x into hi/lo bf16 ----------------------------
__global__ void split_x_kernel(const float* __restrict__ x,
                               unsigned short* __restrict__ hi,
                               unsigned short* __restrict__ lo, int n4) {
  int idx = blockIdx.x * blockDim.x + threadIdx.x;
  int stride = gridDim.x * blockDim.x;
  for (; idx < n4; idx += stride) {
    float4 v = ((const float4*)x)[idx];
    ushort4 h, l;
    h.x = f2bf(v.x); l.x = f2bf(v.x - bf2f(h.x));
    h.y = f2bf(v.y); l.y = f2bf(v.y - bf2f(h.y));
    h.z = f2bf(v.z); l.z = f2bf(v.z - bf2f(h.z));
    h.w = f2bf(v.w); l.w = f2bf(v.w - bf2f(h.w));
    ((ushort4*)hi)[idx] = h;
    ((ushort4*)lo)[idx] = l;
  }
}

// ---------------- prep: split W = [wq;wk;wv] into Bhi/Blo (3072 x 2048) ----
__global__ void split_w_kernel(const float* __restrict__ wq,
                               const float* __restrict__ wk,
                               const float* __restrict__ wv,
                               unsigned short* __restrict__ Bhi,
                               unsigned short* __restrict__ Blo) {
  int idx = blockIdx.x * blockDim.x + threadIdx.x;   // 3072 * 512 float4 items
  int stride = gridDim.x * blockDim.x;
  for (; idx < 3072 * 512; idx += stride) {
    int n = idx >> 9, k4 = idx & 511;
    const float* src;
    if (n < 2048)      src = wq + (size_t)n * 2048;
    else if (n < 2560) src = wk + (size_t)(n - 2048) * 2048;
    else               src = wv + (size_t)(n - 2560) * 2048;
    float4 v = ((const float4*)src)[k4];
    ushort4 h, l;
    h.x = f2bf(v.x); l.x = f2bf(v.x - bf2f(h.x));
    h.y = f2bf(v.y); l.y = f2bf(v.y - bf2f(h.y));
    h.z = f2bf(v.z); l.z = f2bf(v.z - bf2f(h.z));
    h.w = f2bf(v.w); l.w = f2bf(v.w - bf2f(h.w));
    ((ushort4*)Bhi)[idx] = h;
    ((ushort4*)Blo)[idx] = l;
  }
}

// ---------------- prep: RoPE cos/sin table (8192 x 64) ---------------------
__global__ void rope_table_kernel(float2* __restrict__ rt,
                                  const int* __restrict__ pos_off) {
  int idx = blockIdx.x * blockDim.x + threadIdx.x;
  if (idx >= 8192 * 64) return;
  int t = idx >> 6, j = idx & 63;
  double invf = pow(10000.0, -(double)j / 64.0);
  float invf_f = (float)invf;                       // fp32-rounded like XLA
  float p = (float)(t + pos_off[0]);
  float ang = p * invf_f;                           // fp32 product like reference
  double a = (double)ang;
  rt[idx] = make_float2((float)cos(a), (float)sin(a));
}

// ---------------- main GEMM + RoPE epilogue --------------------------------
__global__ __launch_bounds__(256) void gemm_rope_kernel(
    const unsigned short* __restrict__ Ahi, const unsigned short* __restrict__ Alo,
    const unsigned short* __restrict__ Bhi, const unsigned short* __restrict__ Blo,
    const float2* __restrict__ rt, float* __restrict__ out) {
  __shared__ __align__(16) unsigned short lA[128 * 64];
  __shared__ __align__(16) unsigned short lB[128 * 64];

  const int tid  = threadIdx.x;
  const int lane = tid & 63;
  const int wave = tid >> 6;
  const int wr = wave >> 1, wc = wave & 1;
  const int l15 = lane & 15, lk = lane >> 4;

  const int bm = blockIdx.x & 127;   // M tile (fastest-varying: same bn adjacent)
  const int bn = blockIdx.x >> 7;    // N tile 0..23

  f32x4 acc[4][4];
  #pragma unroll
  for (int m = 0; m < 4; ++m)
    #pragma unroll
    for (int n = 0; n < 4; ++n)
      acc[m][n] = (f32x4){0.f, 0.f, 0.f, 0.f};

  for (int kt = 0; kt < 96; ++kt) {
    // segment -> base pointers: [0,32)=(hi,hi)  [32,64)=(hi,lo)  [64,96)=(lo,hi)
    const unsigned short* As = (kt < 64) ? Ahi : Alo;
    const unsigned short* Bs = (kt < 32 || kt >= 64) ? Bhi : Blo;
    const int kcol = (kt & 31) << 6;
    #pragma unroll
    for (int i = 0; i < 4; ++i) {
      const int g = i * 256 + tid;
      const int r = g >> 3, c = (g & 7) << 3;
      const unsigned short* ga = As + (((size_t)(bm * 128 + r)) << 11) + (kcol + c);
      __builtin_amdgcn_global_load_lds(
          (const __attribute__((address_space(1))) void*)ga,
          (__attribute__((address_space(3))) void*)&lA[(g & ~63) << 3], 16, 0, 0);
      const unsigned short* gb = Bs + (((size_t)(bn * 128 + r)) << 11) + (kcol + c);
      __builtin_amdgcn_global_load_lds(
          (const __attribute__((address_space(1))) void*)gb,
          (__attribute__((address_space(3))) void*)&lB[(g & ~63) << 3], 16, 0, 0);
    }
    __syncthreads();

    #pragma unroll
    for (int kk = 0; kk < 2; ++kk) {
      short8 af[4], bfr[4];
      #pragma unroll
      for (int m = 0; m < 4; ++m)
        af[m] = *(const short8*)&lA[(wr * 64 + m * 16 + l15) * 64 + kk * 32 + lk * 8];
      #pragma unroll
      for (int n = 0; n < 4; ++n) {
        // wave wc owns cols {wc*32 + [0,32)} U {wc*32 + 64 + [0,32)}
        const int coln = wc * 32 + (n & 1) * 16 + (n >> 1) * 64;
        bfr[n] = *(const short8*)&lB[(coln + l15) * 64 + kk * 32 + lk * 8];
      }
      #pragma unroll
      for (int m = 0; m < 4; ++m)
        #pragma unroll
        for (int n = 0; n < 4; ++n)
          acc[m][n] = __builtin_amdgcn_mfma_f32_16x16x32_bf16(af[m], bfr[n],
                                                              acc[m][n], 0, 0, 0);
    }
    __syncthreads();
  }

  // ---- epilogue: RoPE in-register + head-transpose scatter ----
  size_t base; int nh, head; bool dorope;
  if (bn < 16)      { base = 0;       head = bn;      nh = 16; dorope = true; }
  else if (bn < 20) { base = Q_BLOCK; head = bn - 16; nh = 4;  dorope = true; }
  else              { base = V_BASE;  head = bn - 20; nh = 4;  dorope = false; }

  #pragma unroll
  for (int m = 0; m < 4; ++m) {
    #pragma unroll
    for (int r = 0; r < 4; ++r) {
      const int row = bm * 128 + wr * 64 + m * 16 + lk * 4 + r;
      const int b = row >> 13, t = row & 8191;
      float* op = out + base + (((size_t)(b * nh + head) * 8192 + t) << 7);
      #pragma unroll
      for (int n0 = 0; n0 < 2; ++n0) {
        const int d1 = wc * 32 + n0 * 16 + l15;            // [0,64)
        const float c1 = acc[m][n0][r];                    // col d1
        const float c2 = acc[m][n0 + 2][r];                // col d1+64
        if (dorope) {
          const float2 cs = rt[(t << 6) + d1];
          op[d1]      = c1 * cs.x - c2 * cs.y;
          op[d1 + 64] = c2 * cs.x + c1 * cs.y;
        } else {
          op[d1]      = c1;
          op[d1 + 64] = c2;
        }
      }
    }
  }
}

// ---------------- fallback: naive fp32, zero workspace ---------------------
// grid (16384, 6), block 256. One block row-pair group: x row staged in LDS,
// each thread computes the (d, d+64) column pair via two fp32 dots + RoPE.
__global__ void fallback_kernel(const float* __restrict__ x,
                                const float* __restrict__ wq,
                                const float* __restrict__ wk,
                                const float* __restrict__ wv,
                                const int* __restrict__ pos_off,
                                float* __restrict__ out) {
  __shared__ float xs[2048];
  const int m = blockIdx.x;
  const int b = m >> 13, t = m & 8191;
  const float* xr = x + (size_t)m * 2048;
  for (int i = threadIdx.x; i < 2048; i += 256) xs[i] = xr[i];
  __syncthreads();

  const int n = blockIdx.y * 256 + threadIdx.x;   // [0,1536)
  const int d = n & 63;
  const float* w; size_t base; int head, nh; bool dorope;
  if (n < 1024)      { head = n >> 6;          w = wq + (size_t)(head * 128 + d) * 2048; base = 0;       nh = 16; dorope = true; }
  else if (n < 1280) { head = (n - 1024) >> 6; w = wk + (size_t)(head * 128 + d) * 2048; base = Q_BLOCK; nh = 4;  dorope = true; }
  else               { head = (n - 1280) >> 6; w = wv + (size_t)(head * 128 + d) * 2048; base = V_BASE;  nh = 4;  dorope = false; }

  const float* w2 = w + 64 * 2048;
  float c1 = 0.f, c2 = 0.f;
  for (int k = 0; k < 2048; ++k) { c1 += xs[k] * w[k]; c2 += xs[k] * w2[k]; }

  float* op = out + base + (((size_t)(b * nh + head) * 8192 + t) << 7);
  if (dorope) {
    double invf = pow(10000.0, -(double)d / 64.0);
    float ang = (float)(t + pos_off[0]) * (float)invf;
    float cs = (float)cos((double)ang), sn = (float)sin((double)ang);
    op[d]      = c1 * cs - c2 * sn;
    op[d + 64] = c2 * cs + c1 * sn;
  } else {
    op[d]      = c1;
    op[d + 64] = c2;
  }
}

// ---------------------------------------------------------------------------
extern "C" void kernel_launch(void* const* d_in, const int* in_sizes, int n_in,
                              void* d_out, int out_size, void* d_ws, size_t ws_size,
                              hipStream_t stream) {
  const float* x  = (const float*)d_in[0];
  const float* wq = (const float*)d_in[1];
  const float* wk = (const float*)d_in[2];
  const float* wv = (const float*)d_in[3];
  const int* pos  = (const int*)d_in[4];
  float* out = (float*)d_out;

  // workspace layout (163.6 MB total)
  const size_t WS_NEEDED = 134217728ull + 25165824ull + 4194304ull;
  if (ws_size < WS_NEEDED) {
    // ws too small for the split-GEMM path: correct-but-slow fallback (no ws).
    fallback_kernel<<<dim3(16384, 6), 256, 0, stream>>>(x, wq, wk, wv, pos, out);
    return;
  }

  unsigned short* Ahi = (unsigned short*)d_ws;      // 33554432 bf16 = 67.1 MB
  unsigned short* Alo = Ahi + 33554432;             // 67.1 MB
  unsigned short* Bhi = Alo + 33554432;             // 3072*2048 = 12.6 MB
  unsigned short* Blo = Bhi + 6291456;              // 12.6 MB
  float2* rt = (float2*)(Blo + 6291456);            // 8192*64*8B = 4.2 MB

  split_x_kernel<<<2048, 256, 0, stream>>>(x, Ahi, Alo, 8388608);
  split_w_kernel<<<2048, 256, 0, stream>>>(wq, wk, wv, Bhi, Blo);
  rope_table_kernel<<<2048, 256, 0, stream>>>(rt, pos);
  gemm_rope_kernel<<<3072, 256, 0, stream>>>(Ahi, Alo, Bhi, Blo, rt, out);
}

// Round 5
// 841.735 us; speedup vs baseline: 1.4194x; 1.4194x over previous
//
#include <hip/hip_runtime.h>
#include <hip/hip_bf16.h>

// ---------------------------------------------------------------------------
// LlamaAttentionWeight: fused QKV projection (fp32 via bf16 split-GEMM) + RoPE
//   x:(2,8192,2048) wq:(2048,2048) wk:(512,2048) wv:(512,2048) pos_offset:int
//   out: qh(2,16,8192,128) | kh(2,4,8192,128) | vh(2,4,8192,128)  (fp32, concat)
//
// C = xhi.whi + xhi.wlo + xlo.whi  (bf16 split products, error ~2^-17)
// Logical GEMM M=16384 N=3072 K'=96x64; kt selects segment base pointers.
//
// GEMM: 256x256 tile, BK=64, 8 waves (2M x 4N), 4 phases/K-tile (quadrants),
//   T2 XOR-swizzle (col8 ^= row&7; linear gload_lds dest + pre-swizzled
//   global src + swizzled ds_read), T3/T4 issue-early/drain-late (stages in
//   ph1-2, one __syncthreads per K-tile), T5 setprio around MFMA clusters.
// Wave wc owns cols {(wc&1)*32+[0,32)} U {+64..} of head (wc>>1) so the RoPE
// pair (d, d+64) sits in the same lane -> in-register RoPE epilogue.
// ---------------------------------------------------------------------------

typedef __attribute__((ext_vector_type(8))) short short8;   // 8 bf16 (4 VGPR)
typedef __attribute__((ext_vector_type(4))) float f32x4;

#define Q_BLOCK  33554432u   // 2*16*8192*128
#define V_BASE   41943040u   // Q_BLOCK + 2*4*8192*128

__device__ __forceinline__ unsigned short f2bf(float f) {
  unsigned u = __float_as_uint(f);
  u += 0x7FFFu + ((u >> 16) & 1u);       // RNE
  return (unsigned short)(u >> 16);
}
__device__ __forceinline__ float bf2f(unsigned short h) {
  return __uint_as_float(((unsigned)h) << 16);
}

// ---------------- prep: split x into hi/lo bf16 ----------------------------
__global__ void split_x_kernel(const float* __restrict__ x,
                               unsigned short* __restrict__ hi,
                               unsigned short* __restrict__ lo, int n4) {
  int idx = blockIdx.x * blockDim.x + threadIdx.x;
  int stride = gridDim.x * blockDim.x;
  for (; idx < n4; idx += stride) {
    float4 v = ((const float4*)x)[idx];
    ushort4 h, l;
    h.x = f2bf(v.x); l.x = f2bf(v.x - bf2f(h.x));
    h.y = f2bf(v.y); l.y = f2bf(v.y - bf2f(h.y));
    h.z = f2bf(v.z); l.z = f2bf(v.z - bf2f(h.z));
    h.w = f2bf(v.w); l.w = f2bf(v.w - bf2f(h.w));
    ((ushort4*)hi)[idx] = h;
    ((ushort4*)lo)[idx] = l;
  }
}

// ---------------- prep: split W = [wq;wk;wv] into Bhi/Blo (3072 x 2048) ----
__global__ void split_w_kernel(const float* __restrict__ wq,
                               const float* __restrict__ wk,
                               const float* __restrict__ wv,
                               unsigned short* __restrict__ Bhi,
                               unsigned short* __restrict__ Blo) {
  int idx = blockIdx.x * blockDim.x + threadIdx.x;   // 3072 * 512 float4 items
  int stride = gridDim.x * blockDim.x;
  for (; idx < 3072 * 512; idx += stride) {
    int n = idx >> 9, k4 = idx & 511;
    const float* src;
    if (n < 2048)      src = wq + (size_t)n * 2048;
    else if (n < 2560) src = wk + (size_t)(n - 2048) * 2048;
    else               src = wv + (size_t)(n - 2560) * 2048;
    float4 v = ((const float4*)src)[k4];
    ushort4 h, l;
    h.x = f2bf(v.x); l.x = f2bf(v.x - bf2f(h.x));
    h.y = f2bf(v.y); l.y = f2bf(v.y - bf2f(h.y));
    h.z = f2bf(v.z); l.z = f2bf(v.z - bf2f(h.z));
    h.w = f2bf(v.w); l.w = f2bf(v.w - bf2f(h.w));
    ((ushort4*)Bhi)[idx] = h;
    ((ushort4*)Blo)[idx] = l;
  }
}

// ---------------- prep: RoPE cos/sin table (8192 x 64) ---------------------
// 64 double-pows per block (LDS-cached); angle = fp32(t+off)*fp32(invf) to
// match the reference bitwise; accurate double range-reduction + f32 sincos.
__global__ void rope_table_kernel(float2* __restrict__ rt,
                                  const int* __restrict__ pos_off) {
  __shared__ float sinv[64];
  if (threadIdx.x < 64)
    sinv[threadIdx.x] = (float)pow(10000.0, -(double)threadIdx.x / 64.0);
  __syncthreads();
  int idx = blockIdx.x * blockDim.x + threadIdx.x;
  int stride = gridDim.x * blockDim.x;
  const int po = pos_off[0];
  for (; idx < 8192 * 64; idx += stride) {
    int t = idx >> 6, j = idx & 63;
    float ang = (float)(t + po) * sinv[j];          // fp32 product like ref
    double a = (double)ang;
    double k = rint(a * 0.15915494309189535);       // 1/(2*pi)
    double r = a - k * 6.283185307179586;           // 2*pi (double)
    float rf = (float)r;
    rt[idx] = make_float2(cosf(rf), sinf(rf));
  }
}

// ---------------- staging helper: one half-tile (128 rows x 64 cols) -------
// Linear LDS dest (gload_lds requirement); global src pre-swizzled with the
// involution chunk8 ^= row&7 so that swizzled ds_reads see original data.
__device__ __forceinline__ void stage_half(unsigned short* dst,
                                           const unsigned short* src,
                                           int growbase, int kcol,
                                           int r0, int c8, int tid) {
  const unsigned short* g0 = src + (size_t)(growbase + r0) * 2048 + kcol + c8 * 8;
  __builtin_amdgcn_global_load_lds(
      (const __attribute__((address_space(1))) void*)g0,
      (__attribute__((address_space(3))) void*)(dst + tid * 8), 16, 0, 0);
  __builtin_amdgcn_global_load_lds(
      (const __attribute__((address_space(1))) void*)(g0 + (size_t)64 * 2048),
      (__attribute__((address_space(3))) void*)(dst + tid * 8 + 4096), 16, 0, 0);
}

// ---------------- main GEMM + RoPE epilogue (256^2, 8 waves, 4 phases) -----
__global__ __launch_bounds__(512, 2) void gemm8_kernel(
    const unsigned short* __restrict__ Ahi, const unsigned short* __restrict__ Alo,
    const unsigned short* __restrict__ Bhi, const unsigned short* __restrict__ Blo,
    const float2* __restrict__ rt, float* __restrict__ out) {
  // A[d][h] at (d*2+h)*8192 shorts; B[d][h] at 32768 + (d*2+h)*8192. 128 KiB.
  __shared__ __align__(16) unsigned short smem[65536];

  const int tid  = threadIdx.x;
  const int lane = tid & 63;
  const int wave = tid >> 6;        // 0..7
  const int wr   = wave >> 2;       // M half (A LDS half this wave reads)
  const int wc   = wave & 3;        // N quarter
  const int bh   = wc >> 1;         // B LDS half this wave reads
  const int l15  = lane & 15, lk = lane >> 4;

  const int swz = (blockIdx.x & 7) * 96 + (blockIdx.x >> 3);  // XCD swizzle
  const int bm = swz & 63;          // 64 M tiles
  const int bn = swz >> 6;          // 12 N tiles

  // staging per-thread constants (rule 21: inverse-swizzled global source)
  const int r0 = tid >> 3;                  // 0..63 (row; +64 for 2nd load)
  const int c8 = (tid & 7) ^ (r0 & 7);      // swizzled 16B chunk
  const int rowA = bm * 256;
  const int rowB = bn * 256;

  f32x4 acc[8][4];
  #pragma unroll
  for (int m = 0; m < 8; ++m)
    #pragma unroll
    for (int n = 0; n < 4; ++n)
      acc[m][n] = (f32x4){0.f, 0.f, 0.f, 0.f};

  // prologue: stage K-tile 0 into dbuf 0 (segment 0 = Ahi,Bhi, kcol 0)
  stage_half(&smem[0],             Ahi, rowA,       0, r0, c8, tid);
  stage_half(&smem[8192],          Ahi, rowA + 128, 0, r0, c8, tid);
  stage_half(&smem[32768],         Bhi, rowB,       0, r0, c8, tid);
  stage_half(&smem[32768 + 8192],  Bhi, rowB + 128, 0, r0, c8, tid);
  __syncthreads();

  for (int kt = 0; kt < 96; ++kt) {
    const int cur = kt & 1, nb = cur ^ 1;
    const int Ab = (cur * 2 + wr) * 8192;          // this wave's A half
    const int Bb = 32768 + (cur * 2 + bh) * 8192;  // this wave's B half
    // next K-tile segment pointers: [0,32)=(hi,hi) [32,64)=(hi,lo) [64,96)=(lo,hi)
    const int kn = kt + 1;
    const unsigned short* Asn = (kn < 64) ? Ahi : Alo;
    const unsigned short* Bsn = (kn < 32 || kn >= 64) ? Bhi : Blo;
    const int kcoln = (kn & 31) << 6;

    short8 af[4][2], bf[4][2];

    // ======== phase 1: quadrant (mh=0, nh=0) ========
    #pragma unroll
    for (int mi = 0; mi < 4; ++mi)
      #pragma unroll
      for (int kk = 0; kk < 2; ++kk) {
        const int rh = mi * 16 + l15;
        const int cs = (kk * 32 + lk * 8) ^ ((rh & 7) << 3);
        af[mi][kk] = *(const short8*)&smem[Ab + rh * 64 + cs];
      }
    #pragma unroll
    for (int ni = 0; ni < 2; ++ni)
      #pragma unroll
      for (int kk = 0; kk < 2; ++kk) {
        const int rh = (wc & 1) * 32 + ni * 16 + l15;
        const int cs = (kk * 32 + lk * 8) ^ ((rh & 7) << 3);
        bf[ni][kk] = *(const short8*)&smem[Bb + rh * 64 + cs];
      }
    if (kt < 95) {  // stage next tile, halves 0 (issue-early)
      stage_half(&smem[(nb * 2 + 0) * 8192],         Asn, rowA,       kcoln, r0, c8, tid);
      stage_half(&smem[32768 + (nb * 2 + 0) * 8192], Bsn, rowB,       kcoln, r0, c8, tid);
    }
    __builtin_amdgcn_s_setprio(1);
    #pragma unroll
    for (int mi = 0; mi < 4; ++mi)
      #pragma unroll
      for (int ni = 0; ni < 2; ++ni)
        #pragma unroll
        for (int kk = 0; kk < 2; ++kk)
          acc[mi][ni] = __builtin_amdgcn_mfma_f32_16x16x32_bf16(
              af[mi][kk], bf[ni][kk], acc[mi][ni], 0, 0, 0);
    __builtin_amdgcn_s_setprio(0);
    __builtin_amdgcn_s_barrier();

    // ======== phase 2: quadrant (mh=0, nh=1) ========
    #pragma unroll
    for (int ni = 0; ni < 2; ++ni)
      #pragma unroll
      for (int kk = 0; kk < 2; ++kk) {
        const int rh = (wc & 1) * 32 + ni * 16 + 64 + l15;
        const int cs = (kk * 32 + lk * 8) ^ ((rh & 7) << 3);
        bf[2 + ni][kk] = *(const short8*)&smem[Bb + rh * 64 + cs];
      }
    if (kt < 95) {  // stage next tile, halves 1
      stage_half(&smem[(nb * 2 + 1) * 8192],         Asn, rowA + 128, kcoln, r0, c8, tid);
      stage_half(&smem[32768 + (nb * 2 + 1) * 8192], Bsn, rowB + 128, kcoln, r0, c8, tid);
    }
    __builtin_amdgcn_s_setprio(1);
    #pragma unroll
    for (int mi = 0; mi < 4; ++mi)
      #pragma unroll
      for (int ni = 0; ni < 2; ++ni)
        #pragma unroll
        for (int kk = 0; kk < 2; ++kk)
          acc[mi][2 + ni] = __builtin_amdgcn_mfma_f32_16x16x32_bf16(
              af[mi][kk], bf[2 + ni][kk], acc[mi][2 + ni], 0, 0, 0);
    __builtin_amdgcn_s_setprio(0);
    __builtin_amdgcn_s_barrier();

    // ======== phase 3: quadrant (mh=1, nh=0) ========
    #pragma unroll
    for (int mi = 0; mi < 4; ++mi)
      #pragma unroll
      for (int kk = 0; kk < 2; ++kk) {
        const int rh = 64 + mi * 16 + l15;
        const int cs = (kk * 32 + lk * 8) ^ ((rh & 7) << 3);
        af[mi][kk] = *(const short8*)&smem[Ab + rh * 64 + cs];
      }
    __builtin_amdgcn_s_setprio(1);
    #pragma unroll
    for (int mi = 0; mi < 4; ++mi)
      #pragma unroll
      for (int ni = 0; ni < 2; ++ni)
        #pragma unroll
        for (int kk = 0; kk < 2; ++kk)
          acc[4 + mi][ni] = __builtin_amdgcn_mfma_f32_16x16x32_bf16(
              af[mi][kk], bf[ni][kk], acc[4 + mi][ni], 0, 0, 0);
    __builtin_amdgcn_s_setprio(0);
    __builtin_amdgcn_s_barrier();

    // ======== phase 4: quadrant (mh=1, nh=1) ========
    __builtin_amdgcn_s_setprio(1);
    #pragma unroll
    for (int mi = 0; mi < 4; ++mi)
      #pragma unroll
      for (int ni = 0; ni < 2; ++ni)
        #pragma unroll
        for (int kk = 0; kk < 2; ++kk)
          acc[4 + mi][2 + ni] = __builtin_amdgcn_mfma_f32_16x16x32_bf16(
              af[mi][kk], bf[2 + ni][kk], acc[4 + mi][2 + ni], 0, 0, 0);
    __builtin_amdgcn_s_setprio(0);
    // K-tile boundary: drains stage loads (issued >=2 phases ago) + protects
    // buffer turnover. The ONLY cross-wave sync with a data dependency.
    __syncthreads();
  }

  // ---- epilogue: RoPE in-register + head-transpose scatter ----
  const int headglob = bn * 2 + (wc >> 1);
  size_t base; int nheads, head; bool dorope;
  if (headglob < 16)      { base = 0;       head = headglob;      nheads = 16; dorope = true; }
  else if (headglob < 20) { base = Q_BLOCK; head = headglob - 16; nheads = 4;  dorope = true; }
  else                    { base = V_BASE;  head = headglob - 20; nheads = 4;  dorope = false; }
  const int dbase = (wc & 1) * 32;

  #pragma unroll
  for (int m = 0; m < 8; ++m) {
    #pragma unroll
    for (int r = 0; r < 4; ++r) {
      const int row = bm * 256 + wr * 128 + m * 16 + lk * 4 + r;
      const int b = row >> 13, trow = row & 8191;
      float* op = out + base + (((size_t)(b * nheads + head) * 8192 + trow) << 7);
      #pragma unroll
      for (int n0 = 0; n0 < 2; ++n0) {
        const int d1 = dbase + n0 * 16 + l15;          // [0,64)
        const float c1 = acc[m][n0][r];                // col d1
        const float c2 = acc[m][n0 + 2][r];            // col d1+64
        if (dorope) {
          const float2 cs = rt[(trow << 6) + d1];
          op[d1]      = c1 * cs.x - c2 * cs.y;
          op[d1 + 64] = c2 * cs.x + c1 * cs.y;
        } else {
          op[d1]      = c1;
          op[d1 + 64] = c2;
        }
      }
    }
  }
}

// ---------------- fallback: naive fp32, zero workspace ---------------------
__global__ void fallback_kernel(const float* __restrict__ x,
                                const float* __restrict__ wq,
                                const float* __restrict__ wk,
                                const float* __restrict__ wv,
                                const int* __restrict__ pos_off,
                                float* __restrict__ out) {
  __shared__ float xs[2048];
  const int m = blockIdx.x;
  const int b = m >> 13, t = m & 8191;
  const float* xr = x + (size_t)m * 2048;
  for (int i = threadIdx.x; i < 2048; i += 256) xs[i] = xr[i];
  __syncthreads();

  const int n = blockIdx.y * 256 + threadIdx.x;   // [0,1536)
  const int d = n & 63;
  const float* w; size_t base; int head, nh; bool dorope;
  if (n < 1024)      { head = n >> 6;          w = wq + (size_t)(head * 128 + d) * 2048; base = 0;       nh = 16; dorope = true; }
  else if (n < 1280) { head = (n - 1024) >> 6; w = wk + (size_t)(head * 128 + d) * 2048; base = Q_BLOCK; nh = 4;  dorope = true; }
  else               { head = (n - 1280) >> 6; w = wv + (size_t)(head * 128 + d) * 2048; base = V_BASE;  nh = 4;  dorope = false; }

  const float* w2 = w + 64 * 2048;
  float c1 = 0.f, c2 = 0.f;
  for (int k = 0; k < 2048; ++k) { c1 += xs[k] * w[k]; c2 += xs[k] * w2[k]; }

  float* op = out + base + (((size_t)(b * nh + head) * 8192 + t) << 7);
  if (dorope) {
    double invf = pow(10000.0, -(double)d / 64.0);
    float ang = (float)(t + pos_off[0]) * (float)invf;
    float cs = (float)cos((double)ang), sn = (float)sin((double)ang);
    op[d]      = c1 * cs - c2 * sn;
    op[d + 64] = c2 * cs + c1 * sn;
  } else {
    op[d]      = c1;
    op[d + 64] = c2;
  }
}

// ---------------------------------------------------------------------------
extern "C" void kernel_launch(void* const* d_in, const int* in_sizes, int n_in,
                              void* d_out, int out_size, void* d_ws, size_t ws_size,
                              hipStream_t stream) {
  const float* x  = (const float*)d_in[0];
  const float* wq = (const float*)d_in[1];
  const float* wk = (const float*)d_in[2];
  const float* wv = (const float*)d_in[3];
  const int* pos  = (const int*)d_in[4];
  float* out = (float*)d_out;

  // workspace layout (163.6 MB total)
  const size_t WS_NEEDED = 134217728ull + 25165824ull + 4194304ull;
  if (ws_size < WS_NEEDED) {
    fallback_kernel<<<dim3(16384, 6), 256, 0, stream>>>(x, wq, wk, wv, pos, out);
    return;
  }

  unsigned short* Ahi = (unsigned short*)d_ws;      // 33554432 bf16 = 67.1 MB
  unsigned short* Alo = Ahi + 33554432;             // 67.1 MB
  unsigned short* Bhi = Alo + 33554432;             // 3072*2048 = 12.6 MB
  unsigned short* Blo = Bhi + 6291456;              // 12.6 MB
  float2* rt = (float2*)(Blo + 6291456);            // 8192*64*8B = 4.2 MB

  split_x_kernel<<<2048, 256, 0, stream>>>(x, Ahi, Alo, 8388608);
  split_w_kernel<<<2048, 256, 0, stream>>>(wq, wk, wv, Bhi, Blo);
  rope_table_kernel<<<512, 256, 0, stream>>>(rt, pos);
  gemm8_kernel<<<768, 512, 0, stream>>>(Ahi, Alo, Bhi, Blo, rt, out);
}